// Round 8
// baseline (717.049 us; speedup 1.0000x reference)
//
#include <hip/hip_runtime.h>
#include <hip/hip_bf16.h>

#define NN 100000      // nodes
#define NR 4           // relations
#define NE 400000      // edges per relation
#define INF 128
#define HF 128
#define OUTF 64

#define WIN 8192       // histogram window (32 KB LDS -> 5 blocks/CU)
#define NWIN 13        // ceil(NN / WIN)
#define SUB 8          // edge-slices per window
#define SLICE (NE / SUB)

typedef __attribute__((ext_vector_type(8))) short s16x8;   // 8 bf16 (4 VGPRs)
typedef __attribute__((ext_vector_type(4))) float f32x4;   // MFMA C/D

// ---------------- windowed LDS degree histogram (no global atomics) ------
__global__ __launch_bounds__(256) void deg_win_kernel(const int* __restrict__ src,
                                                      const int* __restrict__ dst,
                                                      int* __restrict__ parts) {
    __shared__ int hist[WIN];
    int arr = blockIdx.z;
    int r   = blockIdx.y;
    int win = blockIdx.x / SUB;
    int sub = blockIdx.x % SUB;
    const int* idx = (arr ? dst : src) + (size_t)r * NE + (size_t)sub * SLICE;
    int base = win * WIN;
    for (int i = threadIdx.x; i < WIN; i += 256) hist[i] = 0;
    __syncthreads();
    for (int i = threadIdx.x; i < SLICE; i += 256) {
        int v = idx[i] - base;
        if ((unsigned)v < WIN) atomicAdd(&hist[v], 1);
    }
    __syncthreads();
    int* outp = parts + ((((size_t)arr * NR + r) * NWIN + win) * SUB + sub) * WIN;
    for (int i = threadIdx.x; i < WIN; i += 256) outp[i] = hist[i];
}

// reduce partials -> deg_in (for scan) + rsqrt norms
__global__ void red_norm_kernel(const int* __restrict__ parts, int* __restrict__ deg_in_i,
                                float* __restrict__ rno, float* __restrict__ rni) {
    int i = blockIdx.x * blockDim.x + threadIdx.x;
    if (i >= NR * NN) return;
    int r = i / NN, n = i - r * NN;
    int win = n / WIN, off = n % WIN;
    const int* p0 = parts + (((size_t)0 * NR + r) * NWIN + win) * SUB * WIN + off;
    const int* p1 = parts + (((size_t)1 * NR + r) * NWIN + win) * SUB * WIN + off;
    int so = 0, si = 0;
    #pragma unroll
    for (int s = 0; s < SUB; s++) { so += p0[(size_t)s * WIN]; si += p1[(size_t)s * WIN]; }
    deg_in_i[i] = si;
    rno[i] = rsqrtf(fmaxf((float)so, 1.0f));
    rni[i] = rsqrtf(fmaxf((float)si, 1.0f));
}

// ---------------- exclusive scan over deg_in (NR*NN entries) -------------
__global__ void scan_block_kernel(const int* __restrict__ in, int* __restrict__ out,
                                  int* __restrict__ blockSums, int n) {
    __shared__ int sd[256];
    int t = threadIdx.x;
    int base = blockIdx.x * 1024 + t * 4;
    int v[4];
    #pragma unroll
    for (int j = 0; j < 4; j++) v[j] = (base + j < n) ? in[base + j] : 0;
    int ts = v[0] + v[1] + v[2] + v[3];
    sd[t] = ts;
    __syncthreads();
    int acc = ts;
    for (int off = 1; off < 256; off <<= 1) {
        int x = (t >= off) ? sd[t - off] : 0;
        __syncthreads();
        acc += x; sd[t] = acc;
        __syncthreads();
    }
    int run = acc - ts;
    #pragma unroll
    for (int j = 0; j < 4; j++) {
        if (base + j < n) out[base + j] = run;
        run += v[j];
    }
    if (t == 255) blockSums[blockIdx.x] = acc;
}

__global__ void scan_sums_kernel(int* __restrict__ blockSums, int nb) {
    __shared__ int sd[512];
    int t = threadIdx.x;
    int v = (t < nb) ? blockSums[t] : 0;
    sd[t] = v;
    __syncthreads();
    int acc = v;
    for (int off = 1; off < 512; off <<= 1) {
        int x = (t >= off) ? sd[t - off] : 0;
        __syncthreads();
        acc += x; sd[t] = acc;
        __syncthreads();
    }
    if (t < nb) blockSums[t] = acc - v;
}

__global__ void scan_add_kernel(int* __restrict__ row_ptr, const int* __restrict__ blockSums,
                                int* __restrict__ cursor, int n) {
    int i = blockIdx.x * blockDim.x + threadIdx.x;
    if (i < n) {
        int v = row_ptr[i] + blockSums[i >> 10];
        row_ptr[i] = v;
        cursor[i] = v;
    }
    if (i == 0) row_ptr[n] = NR * NE;
}

// ---------------- CSR build: scatter (src,coeff) int2 into dst-sorted ----
__global__ void csr_build_kernel(const int* __restrict__ src, const int* __restrict__ dst,
                                 const float* __restrict__ rno, const float* __restrict__ rni,
                                 int* __restrict__ cursor, int2* __restrict__ edges) {
    int r = blockIdx.y;
    int i = blockIdx.x * blockDim.x + threadIdx.x;
    if (i >= NE) return;
    int s = src[(size_t)r * NE + i];
    int d = dst[(size_t)r * NE + i];
    int pos = atomicAdd(&cursor[(size_t)r * NN + d], 1);
    float c = rno[(size_t)r * NN + s] * rni[(size_t)r * NN + d];
    edges[pos] = make_int2(s, __float_as_int(c));
}

// sum biases across relations
__global__ void bsum_kernel(const float* __restrict__ b1, const float* __restrict__ b2,
                            float* __restrict__ bsum1, float* __restrict__ bsum2) {
    int t = threadIdx.x;
    if (t < HF) {
        float s = 0.f;
        for (int r = 0; r < NR; r++) s += b1[r * HF + t];
        bsum1[t] = s;
    } else if (t < HF + OUTF) {
        int f = t - HF;
        float s = 0.f;
        for (int r = 0; r < NR; r++) s += b2[r * OUTF + f];
        bsum2[f] = s;
    }
}

// Wt1[r][n][k] = bf16(W1[r][k][n]); Wt2[r][n][k] = bf16(W2[r][k][n])
__global__ void conv_w_kernel(const float* __restrict__ W1, const float* __restrict__ W2,
                              __hip_bfloat16* __restrict__ Wt1, __hip_bfloat16* __restrict__ Wt2) {
    int id = blockIdx.x * blockDim.x + threadIdx.x;
    if (id < NR * HF * INF) {
        int r = id >> 14, rem = id & 16383;
        int n_ = rem >> 7, k = rem & 127;
        Wt1[id] = __float2bfloat16(W1[((size_t)r * INF + k) * HF + n_]);
    } else {
        int id2 = id - NR * HF * INF;
        if (id2 < NR * OUTF * HF) {
            int r = id2 >> 13, rem = id2 & 8191;
            int n_ = rem >> 7, k = rem & 127;
            Wt2[id2] = __float2bfloat16(W2[((size_t)r * HF + k) * OUTF + n_]);
        }
    }
}

__device__ __forceinline__ s16x8 pack_bf16x8(float4 a0, float4 a1) {
    union { s16x8 v; __hip_bfloat162 h[4]; } u;
    u.h[0] = __float22bfloat162_rn(make_float2(a0.x, a0.y));
    u.h[1] = __float22bfloat162_rn(make_float2(a0.z, a0.w));
    u.h[2] = __float22bfloat162_rn(make_float2(a1.x, a1.y));
    u.h[3] = __float22bfloat162_rn(make_float2(a1.z, a1.w));
    return u.v;
}

// ---------------- bf16 MFMA GEMM, A-reuse over relations ------------------
// Zb[rel][N][F] = A[N,128] @ Wt[rel][F,128]^T for rel in [0, nrel)
// A fragments loaded ONCE per wave, reused across all relations (A-traffic /4)
template<int F, typename AT>
__global__ __launch_bounds__(256) void gemm_all(const AT* __restrict__ Xb,
                                                const __hip_bfloat16* __restrict__ Wt,
                                                __hip_bfloat16* __restrict__ Zb, int nrel) {
    constexpr int NT = F / 16;
    int wid  = threadIdx.x >> 6;
    int lane = threadIdx.x & 63;
    int quad = lane >> 4;
    int l16  = lane & 15;
    int mw   = blockIdx.x * 64 + wid * 16;
    int mrow = mw + l16; if (mrow >= NN) mrow = NN - 1;

    // A fragments: A[m=l16][k = kb*32 + quad*8 + j], held across the rel loop
    s16x8 afr[4];
    #pragma unroll
    for (int kb = 0; kb < 4; kb++) {
        if constexpr (sizeof(AT) == 4) {
            const float* xr = (const float*)Xb + (size_t)mrow * 128 + kb * 32 + quad * 8;
            float4 a0 = *(const float4*)xr;
            float4 a1 = *(const float4*)(xr + 4);
            afr[kb] = pack_bf16x8(a0, a1);
        } else {
            afr[kb] = *(const s16x8*)((const __hip_bfloat16*)Xb + (size_t)mrow * 128 + kb * 32 + quad * 8);
        }
    }

    __shared__ __hip_bfloat16 lds[4][16][F];   // per-wave disjoint slices

    for (int rel = 0; rel < nrel; rel++) {
        const __hip_bfloat16* W = Wt + (size_t)rel * F * 128;
        __hip_bfloat16* Z = Zb + (size_t)rel * NN * F;

        f32x4 acc[NT];
        #pragma unroll
        for (int nt = 0; nt < NT; nt++) {
            acc[nt] = (f32x4){0.f, 0.f, 0.f, 0.f};
            #pragma unroll
            for (int kb = 0; kb < 4; kb++) {
                s16x8 bfr = *(const s16x8*)(W + (size_t)(nt * 16 + l16) * 128 + kb * 32 + quad * 8);
                acc[nt] = __builtin_amdgcn_mfma_f32_16x16x32_bf16(afr[kb], bfr, acc[nt], 0, 0, 0);
            }
        }

        // epilogue: per-wave LDS transpose -> coalesced 16B stores
        // D: row=quad*4+reg, col=nt*16+l16; wave reads back only its own slice,
        // so no __syncthreads needed (compiler inserts lgkmcnt waits).
        #pragma unroll
        for (int nt = 0; nt < NT; nt++)
            #pragma unroll
            for (int reg = 0; reg < 4; reg++)
                lds[wid][quad * 4 + reg][nt * 16 + l16] = __float2bfloat16(acc[nt][reg]);

        constexpr int PASSES = (16 * F * 2) / 1024;
        const char* lbase = (const char*)&lds[wid][0][0];
        #pragma unroll
        for (int p = 0; p < PASSES; p++) {
            int off = lane * 16 + p * 1024;
            int row = off / (F * 2);
            int cb  = off % (F * 2);
            int g = mw + row;
            if (g < NN)
                *(uint4*)((char*)Z + (size_t)g * F * 2 + cb) = *(const uint4*)(lbase + off);
        }
    }
}

// ---------------- fused CSR gather over rels [r0..r1], 8-wide MLP --------
// plain (cached) loads: nt hints measured as a regression (R6)
template<int F, bool FIRST, bool RELU, bool OUT_F32>
__global__ void gather_fused(const int* __restrict__ row_ptr, const int2* __restrict__ edges,
                             const __hip_bfloat16* __restrict__ Zb,
                             float* __restrict__ outf, __hip_bfloat16* __restrict__ outb,
                             const float* __restrict__ bsum, int r0, int r1) {
    int wid  = threadIdx.x >> 6;
    int lane = threadIdx.x & 63;
    int n = blockIdx.x * (blockDim.x >> 6) + wid;
    if (n >= NN) return;

    if constexpr (F == 128) {
        float2 a;
        if constexpr (FIRST) a = *(const float2*)(bsum + lane * 2);
        else {
            __hip_bfloat162 hv = *(const __hip_bfloat162*)(outb + (size_t)n * 128 + lane * 2);
            a = __bfloat1622float2(hv);
        }
        for (int r = r0; r <= r1; r++) {
            const __hip_bfloat16* Zr = Zb + (size_t)(r - r0) * NN * 128;
            int beg = row_ptr[r * NN + n];
            int end = row_ptr[r * NN + n + 1];
            for (int p = beg; p < end; p += 8) {
                int   ss[8]; float cc[8];
                #pragma unroll
                for (int j = 0; j < 8; j++) {
                    int q = (p + j < end) ? p + j : end - 1;
                    int2 e = edges[q];
                    ss[j] = e.x;
                    cc[j] = (p + j < end) ? __int_as_float(e.y) : 0.f;
                }
                float2 zz[8];
                #pragma unroll
                for (int j = 0; j < 8; j++)
                    zz[j] = __bfloat1622float2(*(const __hip_bfloat162*)(Zr + (size_t)ss[j] * 128 + lane * 2));
                #pragma unroll
                for (int j = 0; j < 8; j++) {
                    a.x = fmaf(cc[j], zz[j].x, a.x);
                    a.y = fmaf(cc[j], zz[j].y, a.y);
                }
            }
        }
        if constexpr (RELU) { a.x = fmaxf(a.x, 0.f); a.y = fmaxf(a.y, 0.f); }
        *(__hip_bfloat162*)(outb + (size_t)n * 128 + lane * 2) = __float22bfloat162_rn(a);
    } else {
        float a = FIRST ? bsum[lane] : 0.f;
        for (int r = r0; r <= r1; r++) {
            const __hip_bfloat16* Zr = Zb + (size_t)(r - r0) * NN * 64;
            int beg = row_ptr[r * NN + n];
            int end = row_ptr[r * NN + n + 1];
            for (int p = beg; p < end; p += 8) {
                int   ss[8]; float cc[8];
                #pragma unroll
                for (int j = 0; j < 8; j++) {
                    int q = (p + j < end) ? p + j : end - 1;
                    int2 e = edges[q];
                    ss[j] = e.x;
                    cc[j] = (p + j < end) ? __int_as_float(e.y) : 0.f;
                }
                float zz[8];
                #pragma unroll
                for (int j = 0; j < 8; j++)
                    zz[j] = __bfloat162float(Zr[(size_t)ss[j] * 64 + lane]);
                #pragma unroll
                for (int j = 0; j < 8; j++) a = fmaf(cc[j], zz[j], a);
            }
        }
        if constexpr (RELU) a = fmaxf(a, 0.f);
        if constexpr (OUT_F32) outf[(size_t)n * 64 + lane] = a;
        else outb[(size_t)n * 64 + lane] = __float2bfloat16(a);
    }
}

extern "C" void kernel_launch(void* const* d_in, const int* in_sizes, int n_in,
                              void* d_out, int out_size, void* d_ws, size_t ws_size,
                              hipStream_t stream) {
    const float* x   = (const float*)d_in[0];
    const int*   src = (const int*)  d_in[1];   // [4, 400000]
    const int*   dst = (const int*)  d_in[2];
    const float* W1  = (const float*)d_in[3];   // [4,128,128]
    const float* b1  = (const float*)d_in[4];   // [4,128]
    const float* W2  = (const float*)d_in[5];   // [4,128,64]
    const float* b2  = (const float*)d_in[6];   // [4,64]
    float* out = (float*)d_out;                 // [100000,64] fp32

    constexpr int RN = NR * NN;                 // 400000
    constexpr int NB = (RN + 1023) / 1024;      // 391

    char* p = (char*)d_ws;
    int*   deg_in_i  = (int*)p;   p += (size_t)RN * 4;
    float* rno       = (float*)p; p += (size_t)RN * 4;
    float* rni       = (float*)p; p += (size_t)RN * 4;
    int*   row_ptr   = (int*)p;   p += ((size_t)RN + 16) * 4;
    int*   cursor    = (int*)p;   p += (size_t)RN * 4;
    int*   blockSums = (int*)p;   p += 1024 * 4;
    int2*  edges     = (int2*)p;  p += (size_t)NR * NE * 8;   // 12.8 MB
    float* bsum1 = (float*)p; p += HF * 4;
    float* bsum2 = (float*)p; p += OUTF * 4;
    __hip_bfloat16* hb  = (__hip_bfloat16*)p; p += (size_t)NN * HF * 2;    // 25.6 MB
    __hip_bfloat16* Wt1 = (__hip_bfloat16*)p; p += (size_t)NR * HF * INF * 2;
    __hip_bfloat16* Wt2 = (__hip_bfloat16*)p; p += (size_t)NR * OUTF * HF * 2;
    size_t fixed = (size_t)(p - (char*)d_ws);
    __hip_bfloat16* Zb = (__hip_bfloat16*)p;
    // Zb: fused path = 4 rels (102.4 MB), split path = 2 rels (51.2 MB)
    bool fused = ws_size >= fixed + (size_t)4 * NN * HF * 2;
    // parts aliases Zb (dead before any GEMM writes): 2*NR*NWIN*SUB*WIN = 27.3 MB
    int* parts = (int*)Zb;

    // ---- CSR build ----
    conv_w_kernel<<<(NR * HF * INF + NR * OUTF * HF + 255) / 256, 256, 0, stream>>>(W1, W2, Wt1, Wt2);
    bsum_kernel<<<1, 192, 0, stream>>>(b1, b2, bsum1, bsum2);
    deg_win_kernel<<<dim3(NWIN * SUB, NR, 2), 256, 0, stream>>>(src, dst, parts);
    red_norm_kernel<<<(RN + 255) / 256, 256, 0, stream>>>(parts, deg_in_i, rno, rni);
    scan_block_kernel<<<NB, 256, 0, stream>>>(deg_in_i, row_ptr, blockSums, RN);
    scan_sums_kernel<<<1, 512, 0, stream>>>(blockSums, NB);
    scan_add_kernel<<<(RN + 255) / 256, 256, 0, stream>>>(row_ptr, blockSums, cursor, RN);
    csr_build_kernel<<<dim3((NE + 255) / 256, NR), 256, 0, stream>>>(
        src, dst, rno, rni, cursor, edges);

    constexpr int GB = (NN + 63) / 64;   // 1563
    constexpr int GG = (NN + 3) / 4;     // 25000

    if (fused) {
        // ---- layer 1: 4-rel A-reuse GEMM + one fused gather ----
        gemm_all<HF, float><<<GB, 256, 0, stream>>>(x, Wt1, Zb, 4);
        gather_fused<HF, true, true, false><<<GG, 256, 0, stream>>>(
            row_ptr, edges, Zb, nullptr, hb, bsum1, 0, 3);
    } else {
        gemm_all<HF, float><<<GB, 256, 0, stream>>>(x, Wt1, Zb, 2);
        gather_fused<HF, true, false, false><<<GG, 256, 0, stream>>>(
            row_ptr, edges, Zb, nullptr, hb, bsum1, 0, 1);
        gemm_all<HF, float><<<GB, 256, 0, stream>>>(x, Wt1 + (size_t)2 * HF * INF, Zb, 2);
        gather_fused<HF, false, true, false><<<GG, 256, 0, stream>>>(
            row_ptr, edges, Zb, nullptr, hb, bsum1, 2, 3);
    }

    // ---- layer 2: 4-rel A-reuse GEMM + one fused gather ----
    gemm_all<OUTF, __hip_bfloat16><<<GB, 256, 0, stream>>>(hb, Wt2, Zb, 4);
    gather_fused<OUTF, true, false, true><<<GG, 256, 0, stream>>>(
        row_ptr, edges, Zb, out, nullptr, bsum2, 0, 3);
}

// Round 9
// 616.489 us; speedup vs baseline: 1.1631x; 1.1631x over previous
//
#include <hip/hip_runtime.h>
#include <hip/hip_bf16.h>

#define NN 100000      // nodes
#define NR 4           // relations
#define NE 400000      // edges per relation
#define INF 128
#define HF 128
#define OUTF 64

#define WIN 8192       // histogram window (32 KB LDS -> 5 blocks/CU)
#define NWIN 13        // ceil(NN / WIN)
#define SUB 8          // edge-slices per window
#define SLICE (NE / SUB)

typedef __attribute__((ext_vector_type(8))) short s16x8;   // 8 bf16 (4 VGPRs)
typedef __attribute__((ext_vector_type(4))) float f32x4;   // MFMA C/D

// ---------------- windowed LDS degree histogram (no global atomics) ------
__global__ __launch_bounds__(256) void deg_win_kernel(const int* __restrict__ src,
                                                      const int* __restrict__ dst,
                                                      int* __restrict__ parts) {
    __shared__ int hist[WIN];
    int arr = blockIdx.z;
    int r   = blockIdx.y;
    int win = blockIdx.x / SUB;
    int sub = blockIdx.x % SUB;
    const int* idx = (arr ? dst : src) + (size_t)r * NE + (size_t)sub * SLICE;
    int base = win * WIN;
    for (int i = threadIdx.x; i < WIN; i += 256) hist[i] = 0;
    __syncthreads();
    for (int i = threadIdx.x; i < SLICE; i += 256) {
        int v = idx[i] - base;
        if ((unsigned)v < WIN) atomicAdd(&hist[v], 1);
    }
    __syncthreads();
    int* outp = parts + ((((size_t)arr * NR + r) * NWIN + win) * SUB + sub) * WIN;
    for (int i = threadIdx.x; i < WIN; i += 256) outp[i] = hist[i];
}

// reduce partials -> per-rel rsqrt norms + total in-degree per dst (for merged CSR)
__global__ void red_norm_kernel(const int* __restrict__ parts, int* __restrict__ deg_tot,
                                float* __restrict__ rno, float* __restrict__ rni) {
    int n = blockIdx.x * blockDim.x + threadIdx.x;
    if (n >= NN) return;
    int win = n / WIN, off = n % WIN;
    int tot = 0;
    #pragma unroll
    for (int r = 0; r < NR; r++) {
        const int* p0 = parts + (((size_t)0 * NR + r) * NWIN + win) * SUB * WIN + off;
        const int* p1 = parts + (((size_t)1 * NR + r) * NWIN + win) * SUB * WIN + off;
        int so = 0, si = 0;
        #pragma unroll
        for (int s = 0; s < SUB; s++) { so += p0[(size_t)s * WIN]; si += p1[(size_t)s * WIN]; }
        rno[(size_t)r * NN + n] = rsqrtf(fmaxf((float)so, 1.0f));
        rni[(size_t)r * NN + n] = rsqrtf(fmaxf((float)si, 1.0f));
        tot += si;
    }
    deg_tot[n] = tot;
}

// ---------------- exclusive scan over deg_tot (NN entries) ---------------
__global__ void scan_block_kernel(const int* __restrict__ in, int* __restrict__ out,
                                  int* __restrict__ blockSums, int n) {
    __shared__ int sd[256];
    int t = threadIdx.x;
    int base = blockIdx.x * 1024 + t * 4;
    int v[4];
    #pragma unroll
    for (int j = 0; j < 4; j++) v[j] = (base + j < n) ? in[base + j] : 0;
    int ts = v[0] + v[1] + v[2] + v[3];
    sd[t] = ts;
    __syncthreads();
    int acc = ts;
    for (int off = 1; off < 256; off <<= 1) {
        int x = (t >= off) ? sd[t - off] : 0;
        __syncthreads();
        acc += x; sd[t] = acc;
        __syncthreads();
    }
    int run = acc - ts;
    #pragma unroll
    for (int j = 0; j < 4; j++) {
        if (base + j < n) out[base + j] = run;
        run += v[j];
    }
    if (t == 255) blockSums[blockIdx.x] = acc;
}

__global__ void scan_sums_kernel(int* __restrict__ blockSums, int nb) {
    __shared__ int sd[512];
    int t = threadIdx.x;
    int v = (t < nb) ? blockSums[t] : 0;
    sd[t] = v;
    __syncthreads();
    int acc = v;
    for (int off = 1; off < 512; off <<= 1) {
        int x = (t >= off) ? sd[t - off] : 0;
        __syncthreads();
        acc += x; sd[t] = acc;
        __syncthreads();
    }
    if (t < nb) blockSums[t] = acc - v;
}

__global__ void scan_add_kernel(int* __restrict__ row_ptr, const int* __restrict__ blockSums,
                                int* __restrict__ cursor, int n) {
    int i = blockIdx.x * blockDim.x + threadIdx.x;
    if (i < n) {
        int v = row_ptr[i] + blockSums[i >> 10];
        row_ptr[i] = v;
        cursor[i] = v;
    }
    if (i == 0) row_ptr[n] = NR * NE;
}

// ---------------- CSR build: ONE dst-keyed list, all relations mixed -----
// edge record: (idx = rel*NN + src, coeff) -> gather addr = Zb + idx*F
__global__ void csr_build_kernel(const int* __restrict__ src, const int* __restrict__ dst,
                                 const float* __restrict__ rno, const float* __restrict__ rni,
                                 int* __restrict__ cursor, int2* __restrict__ edges) {
    int r = blockIdx.y;
    int i = blockIdx.x * blockDim.x + threadIdx.x;
    if (i >= NE) return;
    int s = src[(size_t)r * NE + i];
    int d = dst[(size_t)r * NE + i];
    int pos = atomicAdd(&cursor[d], 1);
    float c = rno[(size_t)r * NN + s] * rni[(size_t)r * NN + d];
    edges[pos] = make_int2(r * NN + s, __float_as_int(c));
}

// sum biases across relations
__global__ void bsum_kernel(const float* __restrict__ b1, const float* __restrict__ b2,
                            float* __restrict__ bsum1, float* __restrict__ bsum2) {
    int t = threadIdx.x;
    if (t < HF) {
        float s = 0.f;
        for (int r = 0; r < NR; r++) s += b1[r * HF + t];
        bsum1[t] = s;
    } else if (t < HF + OUTF) {
        int f = t - HF;
        float s = 0.f;
        for (int r = 0; r < NR; r++) s += b2[r * OUTF + f];
        bsum2[f] = s;
    }
}

// Wt1[r][n][k] = bf16(W1[r][k][n]); Wt2[r][n][k] = bf16(W2[r][k][n])
__global__ void conv_w_kernel(const float* __restrict__ W1, const float* __restrict__ W2,
                              __hip_bfloat16* __restrict__ Wt1, __hip_bfloat16* __restrict__ Wt2) {
    int id = blockIdx.x * blockDim.x + threadIdx.x;
    if (id < NR * HF * INF) {
        int r = id >> 14, rem = id & 16383;
        int n_ = rem >> 7, k = rem & 127;
        Wt1[id] = __float2bfloat16(W1[((size_t)r * INF + k) * HF + n_]);
    } else {
        int id2 = id - NR * HF * INF;
        if (id2 < NR * OUTF * HF) {
            int r = id2 >> 13, rem = id2 & 8191;
            int n_ = rem >> 7, k = rem & 127;
            Wt2[id2] = __float2bfloat16(W2[((size_t)r * HF + k) * OUTF + n_]);
        }
    }
}

__device__ __forceinline__ s16x8 pack_bf16x8(float4 a0, float4 a1) {
    union { s16x8 v; __hip_bfloat162 h[4]; } u;
    u.h[0] = __float22bfloat162_rn(make_float2(a0.x, a0.y));
    u.h[1] = __float22bfloat162_rn(make_float2(a0.z, a0.w));
    u.h[2] = __float22bfloat162_rn(make_float2(a1.x, a1.y));
    u.h[3] = __float22bfloat162_rn(make_float2(a1.z, a1.w));
    return u.v;
}

// ---------------- bf16 MFMA GEMM, A-reuse over relations ------------------
// Zb[rel][N][F] = A[N,128] @ Wt[rel][F,128]^T for rel in [0, nrel)
template<int F, typename AT>
__global__ __launch_bounds__(256) void gemm_all(const AT* __restrict__ Xb,
                                                const __hip_bfloat16* __restrict__ Wt,
                                                __hip_bfloat16* __restrict__ Zb, int nrel) {
    constexpr int NT = F / 16;
    int wid  = threadIdx.x >> 6;
    int lane = threadIdx.x & 63;
    int quad = lane >> 4;
    int l16  = lane & 15;
    int mw   = blockIdx.x * 64 + wid * 16;
    int mrow = mw + l16; if (mrow >= NN) mrow = NN - 1;

    s16x8 afr[4];
    #pragma unroll
    for (int kb = 0; kb < 4; kb++) {
        if constexpr (sizeof(AT) == 4) {
            const float* xr = (const float*)Xb + (size_t)mrow * 128 + kb * 32 + quad * 8;
            float4 a0 = *(const float4*)xr;
            float4 a1 = *(const float4*)(xr + 4);
            afr[kb] = pack_bf16x8(a0, a1);
        } else {
            afr[kb] = *(const s16x8*)((const __hip_bfloat16*)Xb + (size_t)mrow * 128 + kb * 32 + quad * 8);
        }
    }

    __shared__ __hip_bfloat16 lds[4][16][F];   // per-wave disjoint slices

    for (int rel = 0; rel < nrel; rel++) {
        const __hip_bfloat16* W = Wt + (size_t)rel * F * 128;
        __hip_bfloat16* Z = Zb + (size_t)rel * NN * F;

        f32x4 acc[NT];
        #pragma unroll
        for (int nt = 0; nt < NT; nt++) {
            acc[nt] = (f32x4){0.f, 0.f, 0.f, 0.f};
            #pragma unroll
            for (int kb = 0; kb < 4; kb++) {
                s16x8 bfr = *(const s16x8*)(W + (size_t)(nt * 16 + l16) * 128 + kb * 32 + quad * 8);
                acc[nt] = __builtin_amdgcn_mfma_f32_16x16x32_bf16(afr[kb], bfr, acc[nt], 0, 0, 0);
            }
        }

        #pragma unroll
        for (int nt = 0; nt < NT; nt++)
            #pragma unroll
            for (int reg = 0; reg < 4; reg++)
                lds[wid][quad * 4 + reg][nt * 16 + l16] = __float2bfloat16(acc[nt][reg]);

        constexpr int PASSES = (16 * F * 2) / 1024;
        const char* lbase = (const char*)&lds[wid][0][0];
        #pragma unroll
        for (int p = 0; p < PASSES; p++) {
            int off = lane * 16 + p * 1024;
            int row = off / (F * 2);
            int cb  = off % (F * 2);
            int g = mw + row;
            if (g < NN)
                *(uint4*)((char*)Z + (size_t)g * F * 2 + cb) = *(const uint4*)(lbase + off);
        }
    }
}

// ---------------- merged-CSR gather: one segment per node, 8-wide MLP ----
// edge.x = rel*NN+src -> row = Zb + edge.x * F  (Zb is [rel][N][F] flat)
template<int F, bool RELU, bool OUT_F32>
__global__ void gather_merged(const int* __restrict__ row_ptr, const int2* __restrict__ edges,
                              const __hip_bfloat16* __restrict__ Zb,
                              float* __restrict__ outf, __hip_bfloat16* __restrict__ outb,
                              const float* __restrict__ bsum) {
    int wid  = threadIdx.x >> 6;
    int lane = threadIdx.x & 63;
    int n = blockIdx.x * (blockDim.x >> 6) + wid;
    if (n >= NN) return;
    int beg = row_ptr[n];
    int end = row_ptr[n + 1];

    if constexpr (F == 128) {
        float2 a = *(const float2*)(bsum + lane * 2);
        for (int p = beg; p < end; p += 8) {
            int   ss[8]; float cc[8];
            #pragma unroll
            for (int j = 0; j < 8; j++) {
                int q = (p + j < end) ? p + j : end - 1;
                int2 e = edges[q];
                ss[j] = e.x;
                cc[j] = (p + j < end) ? __int_as_float(e.y) : 0.f;
            }
            float2 zz[8];
            #pragma unroll
            for (int j = 0; j < 8; j++)
                zz[j] = __bfloat1622float2(*(const __hip_bfloat162*)(Zb + (size_t)ss[j] * 128 + lane * 2));
            #pragma unroll
            for (int j = 0; j < 8; j++) {
                a.x = fmaf(cc[j], zz[j].x, a.x);
                a.y = fmaf(cc[j], zz[j].y, a.y);
            }
        }
        if constexpr (RELU) { a.x = fmaxf(a.x, 0.f); a.y = fmaxf(a.y, 0.f); }
        *(__hip_bfloat162*)(outb + (size_t)n * 128 + lane * 2) = __float22bfloat162_rn(a);
    } else {
        float a = bsum[lane];
        for (int p = beg; p < end; p += 8) {
            int   ss[8]; float cc[8];
            #pragma unroll
            for (int j = 0; j < 8; j++) {
                int q = (p + j < end) ? p + j : end - 1;
                int2 e = edges[q];
                ss[j] = e.x;
                cc[j] = (p + j < end) ? __int_as_float(e.y) : 0.f;
            }
            float zz[8];
            #pragma unroll
            for (int j = 0; j < 8; j++)
                zz[j] = __bfloat162float(Zb[(size_t)ss[j] * 64 + lane]);
            #pragma unroll
            for (int j = 0; j < 8; j++) a = fmaf(cc[j], zz[j], a);
        }
        if constexpr (RELU) a = fmaxf(a, 0.f);
        if constexpr (OUT_F32) outf[(size_t)n * 64 + lane] = a;
        else outb[(size_t)n * 64 + lane] = __float2bfloat16(a);
    }
}

extern "C" void kernel_launch(void* const* d_in, const int* in_sizes, int n_in,
                              void* d_out, int out_size, void* d_ws, size_t ws_size,
                              hipStream_t stream) {
    const float* x   = (const float*)d_in[0];
    const int*   src = (const int*)  d_in[1];   // [4, 400000]
    const int*   dst = (const int*)  d_in[2];
    const float* W1  = (const float*)d_in[3];   // [4,128,128]
    const float* b1  = (const float*)d_in[4];   // [4,128]
    const float* W2  = (const float*)d_in[5];   // [4,128,64]
    const float* b2  = (const float*)d_in[6];   // [4,64]
    float* out = (float*)d_out;                 // [100000,64] fp32

    constexpr int RN = NR * NN;                 // 400000 (norm arrays)
    constexpr int NB = (NN + 1023) / 1024;      // 98 scan blocks

    char* p = (char*)d_ws;
    int*   deg_tot   = (int*)p;   p += (size_t)NN * 4;
    float* rno       = (float*)p; p += (size_t)RN * 4;
    float* rni       = (float*)p; p += (size_t)RN * 4;
    int*   row_ptr   = (int*)p;   p += ((size_t)NN + 16) * 4;
    int*   cursor    = (int*)p;   p += (size_t)NN * 4;
    int*   blockSums = (int*)p;   p += 1024 * 4;
    int2*  edges     = (int2*)p;  p += (size_t)NR * NE * 8;   // 12.8 MB
    float* bsum1 = (float*)p; p += HF * 4;
    float* bsum2 = (float*)p; p += OUTF * 4;
    __hip_bfloat16* hb  = (__hip_bfloat16*)p; p += (size_t)NN * HF * 2;    // 25.6 MB
    __hip_bfloat16* Wt1 = (__hip_bfloat16*)p; p += (size_t)NR * HF * INF * 2;
    __hip_bfloat16* Wt2 = (__hip_bfloat16*)p; p += (size_t)NR * OUTF * HF * 2;
    __hip_bfloat16* Zb = (__hip_bfloat16*)p;  // 4 rels: 102.4 MB (fused-proven R6-R8)
    // parts aliases Zb (dead before any GEMM writes): 2*NR*NWIN*SUB*WIN = 27.3 MB
    int* parts = (int*)Zb;

    // ---- CSR build (merged dst-keyed list) ----
    conv_w_kernel<<<(NR * HF * INF + NR * OUTF * HF + 255) / 256, 256, 0, stream>>>(W1, W2, Wt1, Wt2);
    bsum_kernel<<<1, 192, 0, stream>>>(b1, b2, bsum1, bsum2);
    deg_win_kernel<<<dim3(NWIN * SUB, NR, 2), 256, 0, stream>>>(src, dst, parts);
    red_norm_kernel<<<(NN + 255) / 256, 256, 0, stream>>>(parts, deg_tot, rno, rni);
    scan_block_kernel<<<NB, 256, 0, stream>>>(deg_tot, row_ptr, blockSums, NN);
    scan_sums_kernel<<<1, 512, 0, stream>>>(blockSums, NB);
    scan_add_kernel<<<(NN + 255) / 256, 256, 0, stream>>>(row_ptr, blockSums, cursor, NN);
    csr_build_kernel<<<dim3((NE + 255) / 256, NR), 256, 0, stream>>>(
        src, dst, rno, rni, cursor, edges);

    constexpr int GB = (NN + 63) / 64;   // 1563
    constexpr int GG = (NN + 3) / 4;     // 25000

    // ---- layer 1: 4-rel A-reuse GEMM + ONE merged gather (bias+relu fused) ----
    gemm_all<HF, float><<<GB, 256, 0, stream>>>(x, Wt1, Zb, 4);
    gather_merged<HF, true, false><<<GG, 256, 0, stream>>>(
        row_ptr, edges, Zb, nullptr, hb, bsum1);

    // ---- layer 2: 4-rel A-reuse GEMM + ONE merged gather ----
    gemm_all<OUTF, __hip_bfloat16><<<GB, 256, 0, stream>>>(hb, Wt2, Zb, 4);
    gather_merged<OUTF, false, true><<<GG, 256, 0, stream>>>(
        row_ptr, edges, Zb, out, nullptr, bsum2);
}